// Round 12
// baseline (229.280 us; speedup 1.0000x reference)
//
#include <hip/hip_runtime.h>

// MPNN: h1 = relu(segsum(feat[src] -> dst) @ W1^T + b1)
//       out = segsum(h1[src] -> dst) @ W2^T + b2
// N=50000, E=800000, d=128.
//
// Round 11->12: gather was L2-thrash-bound (12.8MB bf16 table vs 4MB per-XCD
// L2). aggregate now runs in 4 dimension-slice phases (gridDim.y): each phase
// touches one 64B line per row -> 3.2MB slice working set, L2-resident per
// XCD. 4 lanes/edge x 16 edge slots = 16 gathers in flight per wave.

#define NDIM 128
#define SCAN_BS 512
#define BKT_SHIFT 8                 // 256 nodes per bucket
#define BKT_NODES 256
#define TILE 4096
#define NBK_MAX 256

typedef __attribute__((ext_vector_type(8))) short bf16x8;
typedef __attribute__((ext_vector_type(4))) float f32x4;

__device__ inline unsigned short f2bf_rne(float x) {
    unsigned u = __float_as_uint(x);
    unsigned lsb = (u >> 16) & 1u;
    u += 0x7fffu + lsb;
    return (unsigned short)(u >> 16);
}

__device__ inline unsigned pack_bf2(float lo, float hi) {
    return (unsigned)f2bf_rne(lo) | ((unsigned)f2bf_rne(hi) << 16);
}

// ---------------- f32 -> bf16 conversion: features + W1 + W2 ----------------
__global__ void convert_all(const float* __restrict__ feat, const float* __restrict__ W1,
                            const float* __restrict__ W2,
                            unsigned short* __restrict__ feat_bf,
                            unsigned short* __restrict__ w1_bf,
                            unsigned short* __restrict__ w2_bf, int n8) {
    int i = blockIdx.x * blockDim.x + threadIdx.x;
    const float* srcp;
    unsigned short* dstp;
    int j;
    if (i < n8)                { srcp = feat; dstp = feat_bf; j = i; }
    else if (i < n8 + 2048)    { srcp = W1;   dstp = w1_bf;   j = i - n8; }
    else if (i < n8 + 4096)    { srcp = W2;   dstp = w2_bf;   j = i - n8 - 2048; }
    else return;
    const float4* p = reinterpret_cast<const float4*>(srcp + (size_t)j * 8);
    float4 a = p[0], b = p[1];
    uint4 pk;
    pk.x = pack_bf2(a.x, a.y);
    pk.y = pack_bf2(a.z, a.w);
    pk.z = pack_bf2(b.x, b.y);
    pk.w = pack_bf2(b.z, b.w);
    *reinterpret_cast<uint4*>(dstp + (size_t)j * 8) = pk;
}

// ========== fast CSR build: block-aggregated radix partition ==========
__global__ __launch_bounds__(256) void tile_hist(const int* __restrict__ dst,
                                                 int* __restrict__ hist_g,
                                                 int n_edges, int ntiles, int nbk) {
    __shared__ int lh[NBK_MAX];
    int tblk = blockIdx.x;
    int t = threadIdx.x;
    for (int i = t; i < nbk; i += 256) lh[i] = 0;
    __syncthreads();
    int e0 = tblk * TILE;
    int e1 = min(e0 + TILE, n_edges);
    for (int e = e0 + t; e < e1; e += 256)
        atomicAdd(&lh[dst[e] >> BKT_SHIFT], 1);
    __syncthreads();
    for (int i = t; i < nbk; i += 256)
        hist_g[i * ntiles + tblk] = lh[i];
}

__global__ __launch_bounds__(SCAN_BS) void scan_g_local(int* g, int* tsums, int n) {
    __shared__ int sh[SCAN_BS];
    int t = threadIdx.x;
    int i = blockIdx.x * SCAN_BS + t;
    int v = (i < n) ? g[i] : 0;
    sh[t] = v;
    __syncthreads();
    for (int off = 1; off < SCAN_BS; off <<= 1) {
        int u = (t >= off) ? sh[t - off] : 0;
        __syncthreads();
        sh[t] += u;
        __syncthreads();
    }
    if (i < n) g[i] = sh[t] - v;
    if (t == SCAN_BS - 1) tsums[blockIdx.x] = sh[t];
}

__global__ __launch_bounds__(128) void scan_blocksums(int* __restrict__ block_sums, int nb) {
    __shared__ int sh[128];
    int t = threadIdx.x;
    sh[t] = (t < nb) ? block_sums[t] : 0;
    __syncthreads();
    for (int off = 1; off < 128; off <<= 1) {
        int u = (t >= off) ? sh[t - off] : 0;
        __syncthreads();
        sh[t] += u;
        __syncthreads();
    }
    if (t < nb) block_sums[t] = sh[t];
}

__global__ __launch_bounds__(SCAN_BS) void scan_g_apply(int* g, const int* tsums,
                                                        int* bbase, int n,
                                                        int ntiles, int nbk) {
    int b = blockIdx.x;
    int i = b * SCAN_BS + threadIdx.x;
    if (i >= n) return;
    int add = (b == 0) ? 0 : tsums[b - 1];
    int r = g[i] + add;
    g[i] = r;
    if (i % ntiles == 0) {
        int bk = i / ntiles;
        if (bk < nbk) bbase[bk] = r;
    }
}

__global__ __launch_bounds__(256) void tile_scatter(const int* __restrict__ src,
                                                    const int* __restrict__ dst,
                                                    const int* __restrict__ hist_g,
                                                    unsigned* __restrict__ bdata,
                                                    int n_edges, int ntiles, int nbk) {
    __shared__ int lcur[NBK_MAX];
    __shared__ int lbase[NBK_MAX];
    __shared__ int gbase[NBK_MAX];
    __shared__ unsigned sorted[TILE];
    int tblk = blockIdx.x;
    int t = threadIdx.x;
    for (int i = t; i < nbk; i += 256) lcur[i] = 0;
    __syncthreads();
    int e0 = tblk * TILE;
    int e1 = min(e0 + TILE, n_edges);
    for (int e = e0 + t; e < e1; e += 256)
        atomicAdd(&lcur[dst[e] >> BKT_SHIFT], 1);
    __syncthreads();
    if (t == 0) {
        int run = 0;
        for (int b = 0; b < nbk; ++b) { lbase[b] = run; run += lcur[b]; }
    }
    __syncthreads();
    for (int i = t; i < nbk; i += 256) {
        gbase[i] = hist_g[i * ntiles + tblk];
        lcur[i]  = lbase[i];
    }
    __syncthreads();
    for (int e = e0 + t; e < e1; e += 256) {
        int d = dst[e];
        int s = src[e];
        int b = d >> BKT_SHIFT;
        int p = atomicAdd(&lcur[b], 1);
        sorted[p] = (unsigned)(s & 0xFFFF) | ((unsigned)(d & (BKT_NODES - 1)) << 16)
                  | ((unsigned)b << 24);
    }
    __syncthreads();
    int cnt = e1 - e0;
    for (int j = t; j < cnt; j += 256) {
        unsigned pk = sorted[j];
        int b = pk >> 24;
        bdata[gbase[b] + (j - lbase[b])] = pk;
    }
}

__global__ __launch_bounds__(256) void bucket_sort_rp(const int* __restrict__ bbase,
                                                      const unsigned* __restrict__ bdata,
                                                      int* __restrict__ row_ptr,
                                                      int* __restrict__ col,
                                                      int n_nodes, int n_edges, int nbk) {
    __shared__ int lcnt[BKT_NODES];
    __shared__ int lcur[BKT_NODES];
    int b = blockIdx.x;
    int t = threadIdx.x;
    int node0 = b << BKT_SHIFT;
    int nloc = min(BKT_NODES, n_nodes - node0);
    int base = bbase[b];
    int next = (b + 1 < nbk) ? bbase[b + 1] : n_edges;
    int cnt = next - base;
    lcnt[t] = 0;
    __syncthreads();
    for (int i = t; i < cnt; i += 256)
        atomicAdd(&lcnt[(bdata[base + i] >> 16) & 255], 1);
    __syncthreads();
    int v = lcnt[t];
    lcur[t] = v;
    __syncthreads();
    for (int off = 1; off < 256; off <<= 1) {
        int u = (t >= off) ? lcur[t - off] : 0;
        __syncthreads();
        lcur[t] += u;
        __syncthreads();
    }
    int excl = lcur[t] - v;
    __syncthreads();
    lcur[t] = excl;
    if (t < nloc) row_ptr[node0 + t] = base + excl;
    if (b == nbk - 1 && t == 0) row_ptr[n_nodes] = n_edges;
    __syncthreads();
    for (int i = t; i < cnt; i += 256) {
        unsigned pk = bdata[base + i];
        int pos = atomicAdd(&lcur[(pk >> 16) & 255], 1);
        col[base + pos] = pk & 0xFFFF;
    }
}

// -------- dimension-sliced bf16 gather segment sum (bf16 output) --------
// gridDim.y = 4 slice phases; slice = one 64B line (32 dims) of each row.
// 4 lanes/edge, 16 edge slots/wave -> 16 gathers in flight.
__global__ __launch_bounds__(256) void aggregate_bf_sliced(
        const uint4* __restrict__ feat_bf,    // [N][16] uint4
        const int* __restrict__ row_ptr,
        const int* __restrict__ col,
        uint4* __restrict__ out_bf,           // [N][16] uint4 (bf16)
        int n_nodes) {
    int wid  = (blockIdx.x * blockDim.x + threadIdx.x) >> 6;
    int lane = threadIdx.x & 63;
    if (wid >= n_nodes) return;
    int slice4 = (blockIdx.y << 2) + (lane & 3);   // uint4 index within row
    int slot   = lane >> 2;                        // edge slot 0..15
    int beg = row_ptr[wid];
    int end = row_ptr[wid + 1];
    float acc[8] = {0.f,0.f,0.f,0.f,0.f,0.f,0.f,0.f};

    for (int e = beg + slot; e < end; e += 16) {
        int s = col[e];
        uint4 a = feat_bf[(size_t)s * 16 + slice4];
        unsigned aw[4] = {a.x, a.y, a.z, a.w};
#pragma unroll
        for (int j = 0; j < 4; ++j) {
            acc[2*j]   += __uint_as_float(aw[j] << 16);
            acc[2*j+1] += __uint_as_float(aw[j] & 0xFFFF0000u);
        }
    }
#pragma unroll
    for (int j = 0; j < 8; ++j) {
        acc[j] += __shfl_xor(acc[j], 4, 64);
        acc[j] += __shfl_xor(acc[j], 8, 64);
        acc[j] += __shfl_xor(acc[j], 16, 64);
        acc[j] += __shfl_xor(acc[j], 32, 64);
    }
    if (slot == 0) {
        uint4 pk;
        pk.x = pack_bf2(acc[0], acc[1]);
        pk.y = pack_bf2(acc[2], acc[3]);
        pk.z = pack_bf2(acc[4], acc[5]);
        pk.w = pack_bf2(acc[6], acc[7]);
        out_bf[(size_t)wid * 16 + slice4] = pk;
    }
}

// ---------------- bf16 MFMA linear: out = h @ W^T + b ----------------
template <bool RELU, bool OUTBF>
__global__ __launch_bounds__(256) void linear_mfma(const unsigned short* __restrict__ h_bf,
                                                   const unsigned short* __restrict__ w_bf,
                                                   const float* __restrict__ bias,
                                                   float* __restrict__ out_f,
                                                   unsigned short* __restrict__ out_bf,
                                                   int n_nodes) {
    int t = threadIdx.x;
    int lane = t & 63;
    int wv = t >> 6;                       // 0..3
    int r0 = blockIdx.x * 128 + wv * 32;
    int n1 = n_nodes - 1;
    int ra0 = min(r0 + (lane & 15), n1);
    int ra1 = min(r0 + 16 + (lane & 15), n1);
    int kb = (lane >> 4) * 8;
    int colb = lane & 15;

    f32x4 acc[2][8];
#pragma unroll
    for (int fr = 0; fr < 2; ++fr)
#pragma unroll
        for (int c = 0; c < 8; ++c)
            acc[fr][c] = (f32x4){0.f, 0.f, 0.f, 0.f};

#pragma unroll
    for (int kc = 0; kc < NDIM; kc += 32) {
        bf16x8 a0 = *reinterpret_cast<const bf16x8*>(h_bf + (size_t)ra0 * NDIM + kc + kb);
        bf16x8 a1 = *reinterpret_cast<const bf16x8*>(h_bf + (size_t)ra1 * NDIM + kc + kb);
#pragma unroll
        for (int c = 0; c < 8; ++c) {
            bf16x8 b = *reinterpret_cast<const bf16x8*>(
                w_bf + (size_t)(c * 16 + colb) * NDIM + kc + kb);
            acc[0][c] = __builtin_amdgcn_mfma_f32_16x16x32_bf16(a0, b, acc[0][c], 0, 0, 0);
            acc[1][c] = __builtin_amdgcn_mfma_f32_16x16x32_bf16(a1, b, acc[1][c], 0, 0, 0);
        }
    }

    int orow = (lane >> 4) * 4;
#pragma unroll
    for (int fr = 0; fr < 2; ++fr) {
#pragma unroll
        for (int c = 0; c < 8; ++c) {
            int colg = c * 16 + colb;
            float bv = bias[colg];
#pragma unroll
            for (int reg = 0; reg < 4; ++reg) {
                int row = r0 + fr * 16 + orow + reg;
                if (row >= n_nodes) continue;
                float v = acc[fr][c][reg] + bv;
                if (RELU) v = fmaxf(v, 0.f);
                if (OUTBF) out_bf[(size_t)row * NDIM + colg] = f2bf_rne(v);
                else       out_f[(size_t)row * NDIM + colg] = v;
            }
        }
    }
}

// ================= fallback CSR build + f32 path (safety only) =================
__global__ void hist_dst(const int* __restrict__ dst, int* __restrict__ counts, int n_edges) {
    int i = blockIdx.x * blockDim.x + threadIdx.x;
    if (i < n_edges) atomicAdd(&counts[dst[i]], 1);
}

__global__ __launch_bounds__(SCAN_BS) void scan_apply_fb(int* __restrict__ row_ptr,
                                                         int* __restrict__ cursor,
                                                         const int* __restrict__ block_sums,
                                                         int n, int nb) {
    int b = blockIdx.x;
    int i = b * SCAN_BS + threadIdx.x;
    int add = (b == 0) ? 0 : block_sums[b - 1];
    if (i < n) {
        int r = row_ptr[i] + add;
        row_ptr[i] = r;
        cursor[i]  = r;
    }
    if (i == 0) row_ptr[n] = block_sums[nb - 1];
}

__global__ void fill_csr(const int* __restrict__ src, const int* __restrict__ dst,
                         int* __restrict__ cursor, int* __restrict__ col, int n_edges) {
    int i = blockIdx.x * blockDim.x + threadIdx.x;
    if (i < n_edges) {
        int pos = atomicAdd(&cursor[dst[i]], 1);
        col[pos] = src[i];
    }
}

__global__ void transpose_w2(const float* __restrict__ W1, const float* __restrict__ W2,
                             float* __restrict__ WT1, float* __restrict__ WT2) {
    int tid = blockIdx.x * 256 + threadIdx.x;
    int which = tid >> 14;
    int t = tid & 16383;
    int o = t >> 7;
    int i = t & 127;
    if (which == 0) WT1[i * NDIM + o] = W1[o * NDIM + i];
    else            WT2[i * NDIM + o] = W2[o * NDIM + i];
}

__global__ void aggregate(const float* __restrict__ feat,
                          const int* __restrict__ row_ptr,
                          const int* __restrict__ col,
                          float* __restrict__ out, int n_nodes) {
    int wid  = (blockIdx.x * blockDim.x + threadIdx.x) >> 6;
    int lane = threadIdx.x & 63;
    if (wid >= n_nodes) return;
    int half = lane >> 5;
    int d4   = (lane & 31) << 2;
    int beg = row_ptr[wid];
    int end = row_ptr[wid + 1];
    float ax = 0.f, ay = 0.f, az = 0.f, aw = 0.f;
    int k = beg + half;
    for (; k < end; k += 2) {
        int s0 = col[k];
        float4 v0 = *reinterpret_cast<const float4*>(feat + (size_t)s0 * NDIM + d4);
        ax += v0.x; ay += v0.y; az += v0.z; aw += v0.w;
    }
    ax += __shfl(ax, lane ^ 32, 64);
    ay += __shfl(ay, lane ^ 32, 64);
    az += __shfl(az, lane ^ 32, 64);
    aw += __shfl(aw, lane ^ 32, 64);
    if (half == 0) {
        float4 r; r.x = ax; r.y = ay; r.z = az; r.w = aw;
        *reinterpret_cast<float4*>(out + (size_t)wid * NDIM + d4) = r;
    }
}

template <bool RELU>
__global__ void linear_k(const float* __restrict__ h, const float* __restrict__ WT,
                         const float* __restrict__ bias, float* __restrict__ out,
                         int n_nodes) {
    int tid = blockIdx.x * blockDim.x + threadIdx.x;
    int row = tid >> 5;
    if (row >= n_nodes) return;
    int c4 = (tid & 31) << 2;
    const float4* h4 = reinterpret_cast<const float4*>(h + (size_t)row * NDIM);
    float4 acc = make_float4(0.f, 0.f, 0.f, 0.f);
#pragma unroll 8
    for (int k4 = 0; k4 < 32; ++k4) {
        float4 hv = h4[k4];
        const float* wt = WT + (k4 * 4) * NDIM + c4;
        float4 w0 = *reinterpret_cast<const float4*>(wt);
        float4 w1 = *reinterpret_cast<const float4*>(wt + NDIM);
        float4 w2 = *reinterpret_cast<const float4*>(wt + 2 * NDIM);
        float4 w3 = *reinterpret_cast<const float4*>(wt + 3 * NDIM);
        acc.x = fmaf(hv.x, w0.x, acc.x); acc.y = fmaf(hv.x, w0.y, acc.y);
        acc.z = fmaf(hv.x, w0.z, acc.z); acc.w = fmaf(hv.x, w0.w, acc.w);
        acc.x = fmaf(hv.y, w1.x, acc.x); acc.y = fmaf(hv.y, w1.y, acc.y);
        acc.z = fmaf(hv.y, w1.z, acc.z); acc.w = fmaf(hv.y, w1.w, acc.w);
        acc.x = fmaf(hv.z, w2.x, acc.x); acc.y = fmaf(hv.z, w2.y, acc.y);
        acc.z = fmaf(hv.z, w2.z, acc.z); acc.w = fmaf(hv.z, w2.w, acc.w);
        acc.x = fmaf(hv.w, w3.x, acc.x); acc.y = fmaf(hv.w, w3.y, acc.y);
        acc.z = fmaf(hv.w, w3.z, acc.z); acc.w = fmaf(hv.w, w3.w, acc.w);
    }
    float4 bv = *reinterpret_cast<const float4*>(bias + c4);
    acc.x += bv.x; acc.y += bv.y; acc.z += bv.z; acc.w += bv.w;
    if (RELU) {
        acc.x = fmaxf(acc.x, 0.f); acc.y = fmaxf(acc.y, 0.f);
        acc.z = fmaxf(acc.z, 0.f); acc.w = fmaxf(acc.w, 0.f);
    }
    *reinterpret_cast<float4*>(out + (size_t)row * NDIM + c4) = acc;
}

extern "C" void kernel_launch(void* const* d_in, const int* in_sizes, int n_in,
                              void* d_out, int out_size, void* d_ws, size_t ws_size,
                              hipStream_t stream) {
    const float* features = (const float*)d_in[0];
    const int*   src      = (const int*)d_in[1];
    const int*   dst      = (const int*)d_in[2];
    const float* W1       = (const float*)d_in[3];
    const float* b1       = (const float*)d_in[4];
    const float* W2       = (const float*)d_in[5];
    const float* b2       = (const float*)d_in[6];
    float* out = (float*)d_out;

    int n_nodes = in_sizes[0] / NDIM;   // 50000
    int n_edges = in_sizes[1];          // 800000
    int nbk = (n_nodes + BKT_NODES - 1) >> BKT_SHIFT;   // 196
    int ntiles = (n_edges + TILE - 1) / TILE;           // 196
    int rp_pad = ((n_nodes + 1 + 3) / 4) * 4;

    // ---- ws layout ----
    char* base = (char*)d_ws;
    unsigned short* hneigh_bf = (unsigned short*)base;                     // N*128 bf16
    unsigned short* w1_bf  = hneigh_bf + (size_t)n_nodes * NDIM;           // 16384
    unsigned short* w2_bf  = w1_bf + NDIM * NDIM;                          // 16384
    int*   row_ptr = (int*)(w2_bf + NDIM * NDIM);                          // rp_pad
    int*   col     = row_ptr + rp_pad;                                     // E
    unsigned short* feat_bf = (unsigned short*)(col + n_edges);            // N*128 bf16
    int*      hist_g = (int*)(feat_bf + (size_t)n_nodes * NDIM);           // nbk*ntiles
    int*      bbase  = hist_g + (size_t)nbk * ntiles;                      // nbk
    int*      tsums  = bbase + ((nbk + 3) / 4) * 4;                        // 128
    unsigned* bdata  = (unsigned*)(tsums + 128);                           // E
    // fallback-only
    float* WT1    = (float*)(bdata + n_edges);
    float* WT2    = WT1 + NDIM * NDIM;
    int*   counts = (int*)(WT2 + NDIM * NDIM);
    int*   cursor = counts + n_nodes;
    float* hneigh_f = (float*)(cursor + n_nodes);

    size_t needed_fast = (char*)(bdata + n_edges) - base;
    size_t needed_fb   = (char*)(hneigh_f + (size_t)n_nodes * NDIM) - base;

    unsigned short* h1_bf = (unsigned short*)d_out;

    int eb = (n_edges + 255) / 256;
    int nscan = nbk * ntiles;
    int nsb = (nscan + SCAN_BS - 1) / SCAN_BS;
    bool fast = (ws_size >= needed_fast) && (n_nodes <= 65536)
              && (nbk <= NBK_MAX) && (nsb <= 128);

    if (fast) {
        int n8 = n_nodes * (NDIM / 8);
        convert_all<<<(n8 + 4096 + 255) / 256, 256, 0, stream>>>(
            features, W1, W2, feat_bf, w1_bf, w2_bf, n8);

        // ---- CSR build ----
        tile_hist<<<ntiles, 256, 0, stream>>>(dst, hist_g, n_edges, ntiles, nbk);
        scan_g_local<<<nsb, SCAN_BS, 0, stream>>>(hist_g, tsums, nscan);
        scan_blocksums<<<1, 128, 0, stream>>>(tsums, nsb);
        scan_g_apply<<<nsb, SCAN_BS, 0, stream>>>(hist_g, tsums, bbase, nscan, ntiles, nbk);
        tile_scatter<<<ntiles, 256, 0, stream>>>(src, dst, hist_g, bdata,
                                                 n_edges, ntiles, nbk);
        bucket_sort_rp<<<nbk, 256, 0, stream>>>(bbase, bdata, row_ptr, col,
                                                n_nodes, n_edges, nbk);

        dim3 ag((n_nodes * 64 + 255) / 256, 4);
        int lb = (n_nodes + 127) / 128;

        // ---- Layer 1 ----
        aggregate_bf_sliced<<<ag, 256, 0, stream>>>((const uint4*)feat_bf, row_ptr, col,
                                                    (uint4*)hneigh_bf, n_nodes);
        linear_mfma<true, true><<<lb, 256, 0, stream>>>(hneigh_bf, w1_bf, b1,
                                                        nullptr, h1_bf, n_nodes);
        // ---- Layer 2 ----
        aggregate_bf_sliced<<<ag, 256, 0, stream>>>((const uint4*)h1_bf, row_ptr, col,
                                                    (uint4*)hneigh_bf, n_nodes);
        linear_mfma<false, false><<<lb, 256, 0, stream>>>(hneigh_bf, w2_bf, b2,
                                                          out, nullptr, n_nodes);
    } else if (ws_size >= needed_fb) {
        // ---- f32 fallback ----
        transpose_w2<<<128, 256, 0, stream>>>(W1, W2, WT1, WT2);
        hipMemsetAsync(counts, 0, (size_t)n_nodes * sizeof(int), stream);
        hist_dst<<<eb, 256, 0, stream>>>(dst, counts, n_edges);
        int nb = (n_nodes + SCAN_BS - 1) / SCAN_BS;
        scan_g_local<<<nb, SCAN_BS, 0, stream>>>(counts, tsums, n_nodes);
        scan_blocksums<<<1, 128, 0, stream>>>(tsums, nb);
        scan_apply_fb<<<nb, SCAN_BS, 0, stream>>>(counts, cursor, tsums, n_nodes, nb);
        hipMemcpyAsync(row_ptr, counts, (size_t)(n_nodes + 1) * sizeof(int),
                       hipMemcpyDeviceToDevice, stream);
        fill_csr<<<eb, 256, 0, stream>>>(src, dst, cursor, col, n_edges);

        int ab = (int)(((long)n_nodes * 64 + 255) / 256);
        int lk = (n_nodes * 32 + 255) / 256;
        aggregate<<<ab, 256, 0, stream>>>(features, row_ptr, col, hneigh_f, n_nodes);
        linear_k<true><<<lk, 256, 0, stream>>>(hneigh_f, WT1, b1, out, n_nodes);
        aggregate<<<ab, 256, 0, stream>>>(out, row_ptr, col, hneigh_f, n_nodes);
        linear_k<false><<<lk, 256, 0, stream>>>(hneigh_f, WT2, b2, out, n_nodes);
    }
}

// Round 13
// 148.671 us; speedup vs baseline: 1.5422x; 1.5422x over previous
//
#include <hip/hip_runtime.h>

// MPNN: h1 = relu(segsum(feat[src] -> dst) @ W1^T + b1)
//       out = segsum(h1[src] -> dst) @ W2^T + b2
// N=50000, E=800000, d=128.
//
// Round 12->13: REVERT the dimension-sliced gather (round 12: FETCH 203MB =
// E*64B*4 exactly -> zero reuse; y-slices co-ran, thrashing L2 with 4x the
// requests). Back to round-11 whole-row gather (16 lanes/edge, 4 slots,
// unroll-2). One new change: scan_blocksums kernel folded into scan_g_apply
// (each block tree-reduces tsums[0..b) in LDS) -> one fewer dispatch in the
// CSR chain.

#define NDIM 128
#define SCAN_BS 512
#define BKT_SHIFT 8                 // 256 nodes per bucket
#define BKT_NODES 256
#define TILE 4096
#define NBK_MAX 256

typedef __attribute__((ext_vector_type(8))) short bf16x8;
typedef __attribute__((ext_vector_type(4))) float f32x4;

__device__ inline unsigned short f2bf_rne(float x) {
    unsigned u = __float_as_uint(x);
    unsigned lsb = (u >> 16) & 1u;
    u += 0x7fffu + lsb;
    return (unsigned short)(u >> 16);
}

__device__ inline unsigned pack_bf2(float lo, float hi) {
    return (unsigned)f2bf_rne(lo) | ((unsigned)f2bf_rne(hi) << 16);
}

// ---------------- f32 -> bf16 conversion: features + W1 + W2 ----------------
__global__ void convert_all(const float* __restrict__ feat, const float* __restrict__ W1,
                            const float* __restrict__ W2,
                            unsigned short* __restrict__ feat_bf,
                            unsigned short* __restrict__ w1_bf,
                            unsigned short* __restrict__ w2_bf, int n8) {
    int i = blockIdx.x * blockDim.x + threadIdx.x;
    const float* srcp;
    unsigned short* dstp;
    int j;
    if (i < n8)                { srcp = feat; dstp = feat_bf; j = i; }
    else if (i < n8 + 2048)    { srcp = W1;   dstp = w1_bf;   j = i - n8; }
    else if (i < n8 + 4096)    { srcp = W2;   dstp = w2_bf;   j = i - n8 - 2048; }
    else return;
    const float4* p = reinterpret_cast<const float4*>(srcp + (size_t)j * 8);
    float4 a = p[0], b = p[1];
    uint4 pk;
    pk.x = pack_bf2(a.x, a.y);
    pk.y = pack_bf2(a.z, a.w);
    pk.z = pack_bf2(b.x, b.y);
    pk.w = pack_bf2(b.z, b.w);
    *reinterpret_cast<uint4*>(dstp + (size_t)j * 8) = pk;
}

// ========== fast CSR build: block-aggregated radix partition ==========
__global__ __launch_bounds__(256) void tile_hist(const int* __restrict__ dst,
                                                 int* __restrict__ hist_g,
                                                 int n_edges, int ntiles, int nbk) {
    __shared__ int lh[NBK_MAX];
    int tblk = blockIdx.x;
    int t = threadIdx.x;
    for (int i = t; i < nbk; i += 256) lh[i] = 0;
    __syncthreads();
    int e0 = tblk * TILE;
    int e1 = min(e0 + TILE, n_edges);
    for (int e = e0 + t; e < e1; e += 256)
        atomicAdd(&lh[dst[e] >> BKT_SHIFT], 1);
    __syncthreads();
    for (int i = t; i < nbk; i += 256)
        hist_g[i * ntiles + tblk] = lh[i];
}

__global__ __launch_bounds__(SCAN_BS) void scan_g_local(int* g, int* tsums, int n) {
    __shared__ int sh[SCAN_BS];
    int t = threadIdx.x;
    int i = blockIdx.x * SCAN_BS + t;
    int v = (i < n) ? g[i] : 0;
    sh[t] = v;
    __syncthreads();
    for (int off = 1; off < SCAN_BS; off <<= 1) {
        int u = (t >= off) ? sh[t - off] : 0;
        __syncthreads();
        sh[t] += u;
        __syncthreads();
    }
    if (i < n) g[i] = sh[t] - v;
    if (t == SCAN_BS - 1) tsums[blockIdx.x] = sh[t];
}

// apply with inline offset computation: block b sums tsums[0..b) via LDS tree.
// Requires gridDim.x <= 128.
__global__ __launch_bounds__(SCAN_BS) void scan_g_apply2(int* g, const int* tsums,
                                                         int* bbase, int n,
                                                         int ntiles, int nbk) {
    __shared__ int part[128];
    int t = threadIdx.x;
    int b = blockIdx.x;
    if (t < 128) part[t] = (t < b) ? tsums[t] : 0;
    __syncthreads();
    for (int off = 64; off > 0; off >>= 1) {
        if (t < off) part[t] += part[t + off];
        __syncthreads();
    }
    int add = part[0];
    int i = b * SCAN_BS + t;
    if (i >= n) return;
    int r = g[i] + add;
    g[i] = r;
    if (i % ntiles == 0) {
        int bk = i / ntiles;
        if (bk < nbk) bbase[bk] = r;
    }
}

__global__ __launch_bounds__(128) void scan_blocksums(int* __restrict__ block_sums, int nb) {
    __shared__ int sh[128];
    int t = threadIdx.x;
    sh[t] = (t < nb) ? block_sums[t] : 0;
    __syncthreads();
    for (int off = 1; off < 128; off <<= 1) {
        int u = (t >= off) ? sh[t - off] : 0;
        __syncthreads();
        sh[t] += u;
        __syncthreads();
    }
    if (t < nb) block_sums[t] = sh[t];
}

__global__ __launch_bounds__(256) void tile_scatter(const int* __restrict__ src,
                                                    const int* __restrict__ dst,
                                                    const int* __restrict__ hist_g,
                                                    unsigned* __restrict__ bdata,
                                                    int n_edges, int ntiles, int nbk) {
    __shared__ int lcur[NBK_MAX];
    __shared__ int lbase[NBK_MAX];
    __shared__ int gbase[NBK_MAX];
    __shared__ unsigned sorted[TILE];
    int tblk = blockIdx.x;
    int t = threadIdx.x;
    for (int i = t; i < nbk; i += 256) lcur[i] = 0;
    __syncthreads();
    int e0 = tblk * TILE;
    int e1 = min(e0 + TILE, n_edges);
    for (int e = e0 + t; e < e1; e += 256)
        atomicAdd(&lcur[dst[e] >> BKT_SHIFT], 1);
    __syncthreads();
    if (t == 0) {
        int run = 0;
        for (int b = 0; b < nbk; ++b) { lbase[b] = run; run += lcur[b]; }
    }
    __syncthreads();
    for (int i = t; i < nbk; i += 256) {
        gbase[i] = hist_g[i * ntiles + tblk];
        lcur[i]  = lbase[i];
    }
    __syncthreads();
    for (int e = e0 + t; e < e1; e += 256) {
        int d = dst[e];
        int s = src[e];
        int b = d >> BKT_SHIFT;
        int p = atomicAdd(&lcur[b], 1);
        sorted[p] = (unsigned)(s & 0xFFFF) | ((unsigned)(d & (BKT_NODES - 1)) << 16)
                  | ((unsigned)b << 24);
    }
    __syncthreads();
    int cnt = e1 - e0;
    for (int j = t; j < cnt; j += 256) {
        unsigned pk = sorted[j];
        int b = pk >> 24;
        bdata[gbase[b] + (j - lbase[b])] = pk;
    }
}

__global__ __launch_bounds__(256) void bucket_sort_rp(const int* __restrict__ bbase,
                                                      const unsigned* __restrict__ bdata,
                                                      int* __restrict__ row_ptr,
                                                      int* __restrict__ col,
                                                      int n_nodes, int n_edges, int nbk) {
    __shared__ int lcnt[BKT_NODES];
    __shared__ int lcur[BKT_NODES];
    int b = blockIdx.x;
    int t = threadIdx.x;
    int node0 = b << BKT_SHIFT;
    int nloc = min(BKT_NODES, n_nodes - node0);
    int base = bbase[b];
    int next = (b + 1 < nbk) ? bbase[b + 1] : n_edges;
    int cnt = next - base;
    lcnt[t] = 0;
    __syncthreads();
    for (int i = t; i < cnt; i += 256)
        atomicAdd(&lcnt[(bdata[base + i] >> 16) & 255], 1);
    __syncthreads();
    int v = lcnt[t];
    lcur[t] = v;
    __syncthreads();
    for (int off = 1; off < 256; off <<= 1) {
        int u = (t >= off) ? lcur[t - off] : 0;
        __syncthreads();
        lcur[t] += u;
        __syncthreads();
    }
    int excl = lcur[t] - v;
    __syncthreads();
    lcur[t] = excl;
    if (t < nloc) row_ptr[node0 + t] = base + excl;
    if (b == nbk - 1 && t == 0) row_ptr[n_nodes] = n_edges;
    __syncthreads();
    for (int i = t; i < cnt; i += 256) {
        unsigned pk = bdata[base + i];
        int pos = atomicAdd(&lcur[(pk >> 16) & 255], 1);
        col[base + pos] = pk & 0xFFFF;
    }
}

// ---------------- bf16 gather-side segment sum (round-11 form) ----------------
// One wave per dst node; 16 lanes/edge (4 edge slots), 16B/lane, unroll-2.
__global__ void aggregate_bf(const uint4* __restrict__ feat_bf,   // [N][16] uint4
                             const int* __restrict__ row_ptr,
                             const int* __restrict__ col,
                             uint4* __restrict__ out_bf,          // [N][16] uint4 (bf16)
                             int n_nodes) {
    int wid  = (blockIdx.x * blockDim.x + threadIdx.x) >> 6;
    int lane = threadIdx.x & 63;
    if (wid >= n_nodes) return;
    int sub = lane >> 4;            // edge slot 0..3
    int d   = lane & 15;            // 16B chunk within row
    int beg = row_ptr[wid];
    int end = row_ptr[wid + 1];
    float acc[8] = {0.f,0.f,0.f,0.f,0.f,0.f,0.f,0.f};

    int e = beg + sub;
    for (; e + 4 < end; e += 8) {
        int s0 = col[e];
        int s1 = col[e + 4];
        uint4 a = feat_bf[(size_t)s0 * 16 + d];
        uint4 b = feat_bf[(size_t)s1 * 16 + d];
        unsigned aw[4] = {a.x, a.y, a.z, a.w};
        unsigned bw[4] = {b.x, b.y, b.z, b.w};
#pragma unroll
        for (int j = 0; j < 4; ++j) {
            acc[2*j]   += __uint_as_float(aw[j] << 16);
            acc[2*j+1] += __uint_as_float(aw[j] & 0xFFFF0000u);
            acc[2*j]   += __uint_as_float(bw[j] << 16);
            acc[2*j+1] += __uint_as_float(bw[j] & 0xFFFF0000u);
        }
    }
    for (; e < end; e += 4) {
        int s0 = col[e];
        uint4 a = feat_bf[(size_t)s0 * 16 + d];
        unsigned aw[4] = {a.x, a.y, a.z, a.w};
#pragma unroll
        for (int j = 0; j < 4; ++j) {
            acc[2*j]   += __uint_as_float(aw[j] << 16);
            acc[2*j+1] += __uint_as_float(aw[j] & 0xFFFF0000u);
        }
    }
#pragma unroll
    for (int j = 0; j < 8; ++j) {
        acc[j] += __shfl_xor(acc[j], 16, 64);
        acc[j] += __shfl_xor(acc[j], 32, 64);
    }
    if (sub == 0) {
        uint4 pk;
        pk.x = pack_bf2(acc[0], acc[1]);
        pk.y = pack_bf2(acc[2], acc[3]);
        pk.z = pack_bf2(acc[4], acc[5]);
        pk.w = pack_bf2(acc[6], acc[7]);
        out_bf[(size_t)wid * 16 + d] = pk;
    }
}

// ---------------- bf16 MFMA linear: out = h @ W^T + b ----------------
template <bool RELU, bool OUTBF>
__global__ __launch_bounds__(256) void linear_mfma(const unsigned short* __restrict__ h_bf,
                                                   const unsigned short* __restrict__ w_bf,
                                                   const float* __restrict__ bias,
                                                   float* __restrict__ out_f,
                                                   unsigned short* __restrict__ out_bf,
                                                   int n_nodes) {
    int t = threadIdx.x;
    int lane = t & 63;
    int wv = t >> 6;                       // 0..3
    int r0 = blockIdx.x * 128 + wv * 32;
    int n1 = n_nodes - 1;
    int ra0 = min(r0 + (lane & 15), n1);
    int ra1 = min(r0 + 16 + (lane & 15), n1);
    int kb = (lane >> 4) * 8;
    int colb = lane & 15;

    f32x4 acc[2][8];
#pragma unroll
    for (int fr = 0; fr < 2; ++fr)
#pragma unroll
        for (int c = 0; c < 8; ++c)
            acc[fr][c] = (f32x4){0.f, 0.f, 0.f, 0.f};

#pragma unroll
    for (int kc = 0; kc < NDIM; kc += 32) {
        bf16x8 a0 = *reinterpret_cast<const bf16x8*>(h_bf + (size_t)ra0 * NDIM + kc + kb);
        bf16x8 a1 = *reinterpret_cast<const bf16x8*>(h_bf + (size_t)ra1 * NDIM + kc + kb);
#pragma unroll
        for (int c = 0; c < 8; ++c) {
            bf16x8 b = *reinterpret_cast<const bf16x8*>(
                w_bf + (size_t)(c * 16 + colb) * NDIM + kc + kb);
            acc[0][c] = __builtin_amdgcn_mfma_f32_16x16x32_bf16(a0, b, acc[0][c], 0, 0, 0);
            acc[1][c] = __builtin_amdgcn_mfma_f32_16x16x32_bf16(a1, b, acc[1][c], 0, 0, 0);
        }
    }

    int orow = (lane >> 4) * 4;
#pragma unroll
    for (int fr = 0; fr < 2; ++fr) {
#pragma unroll
        for (int c = 0; c < 8; ++c) {
            int colg = c * 16 + colb;
            float bv = bias[colg];
#pragma unroll
            for (int reg = 0; reg < 4; ++reg) {
                int row = r0 + fr * 16 + orow + reg;
                if (row >= n_nodes) continue;
                float v = acc[fr][c][reg] + bv;
                if (RELU) v = fmaxf(v, 0.f);
                if (OUTBF) out_bf[(size_t)row * NDIM + colg] = f2bf_rne(v);
                else       out_f[(size_t)row * NDIM + colg] = v;
            }
        }
    }
}

// ================= fallback CSR build + f32 path (safety only) =================
__global__ void hist_dst(const int* __restrict__ dst, int* __restrict__ counts, int n_edges) {
    int i = blockIdx.x * blockDim.x + threadIdx.x;
    if (i < n_edges) atomicAdd(&counts[dst[i]], 1);
}

__global__ __launch_bounds__(SCAN_BS) void scan_apply_fb(int* __restrict__ row_ptr,
                                                         int* __restrict__ cursor,
                                                         const int* __restrict__ block_sums,
                                                         int n, int nb) {
    int b = blockIdx.x;
    int i = b * SCAN_BS + threadIdx.x;
    int add = (b == 0) ? 0 : block_sums[b - 1];
    if (i < n) {
        int r = row_ptr[i] + add;
        row_ptr[i] = r;
        cursor[i]  = r;
    }
    if (i == 0) row_ptr[n] = block_sums[nb - 1];
}

__global__ void fill_csr(const int* __restrict__ src, const int* __restrict__ dst,
                         int* __restrict__ cursor, int* __restrict__ col, int n_edges) {
    int i = blockIdx.x * blockDim.x + threadIdx.x;
    if (i < n_edges) {
        int pos = atomicAdd(&cursor[dst[i]], 1);
        col[pos] = src[i];
    }
}

__global__ void transpose_w2(const float* __restrict__ W1, const float* __restrict__ W2,
                             float* __restrict__ WT1, float* __restrict__ WT2) {
    int tid = blockIdx.x * 256 + threadIdx.x;
    int which = tid >> 14;
    int t = tid & 16383;
    int o = t >> 7;
    int i = t & 127;
    if (which == 0) WT1[i * NDIM + o] = W1[o * NDIM + i];
    else            WT2[i * NDIM + o] = W2[o * NDIM + i];
}

__global__ void aggregate(const float* __restrict__ feat,
                          const int* __restrict__ row_ptr,
                          const int* __restrict__ col,
                          float* __restrict__ out, int n_nodes) {
    int wid  = (blockIdx.x * blockDim.x + threadIdx.x) >> 6;
    int lane = threadIdx.x & 63;
    if (wid >= n_nodes) return;
    int half = lane >> 5;
    int d4   = (lane & 31) << 2;
    int beg = row_ptr[wid];
    int end = row_ptr[wid + 1];
    float ax = 0.f, ay = 0.f, az = 0.f, aw = 0.f;
    int k = beg + half;
    for (; k < end; k += 2) {
        int s0 = col[k];
        float4 v0 = *reinterpret_cast<const float4*>(feat + (size_t)s0 * NDIM + d4);
        ax += v0.x; ay += v0.y; az += v0.z; aw += v0.w;
    }
    ax += __shfl(ax, lane ^ 32, 64);
    ay += __shfl(ay, lane ^ 32, 64);
    az += __shfl(az, lane ^ 32, 64);
    aw += __shfl(aw, lane ^ 32, 64);
    if (half == 0) {
        float4 r; r.x = ax; r.y = ay; r.z = az; r.w = aw;
        *reinterpret_cast<float4*>(out + (size_t)wid * NDIM + d4) = r;
    }
}

template <bool RELU>
__global__ void linear_k(const float* __restrict__ h, const float* __restrict__ WT,
                         const float* __restrict__ bias, float* __restrict__ out,
                         int n_nodes) {
    int tid = blockIdx.x * blockDim.x + threadIdx.x;
    int row = tid >> 5;
    if (row >= n_nodes) return;
    int c4 = (tid & 31) << 2;
    const float4* h4 = reinterpret_cast<const float4*>(h + (size_t)row * NDIM);
    float4 acc = make_float4(0.f, 0.f, 0.f, 0.f);
#pragma unroll 8
    for (int k4 = 0; k4 < 32; ++k4) {
        float4 hv = h4[k4];
        const float* wt = WT + (k4 * 4) * NDIM + c4;
        float4 w0 = *reinterpret_cast<const float4*>(wt);
        float4 w1 = *reinterpret_cast<const float4*>(wt + NDIM);
        float4 w2 = *reinterpret_cast<const float4*>(wt + 2 * NDIM);
        float4 w3 = *reinterpret_cast<const float4*>(wt + 3 * NDIM);
        acc.x = fmaf(hv.x, w0.x, acc.x); acc.y = fmaf(hv.x, w0.y, acc.y);
        acc.z = fmaf(hv.x, w0.z, acc.z); acc.w = fmaf(hv.x, w0.w, acc.w);
        acc.x = fmaf(hv.y, w1.x, acc.x); acc.y = fmaf(hv.y, w1.y, acc.y);
        acc.z = fmaf(hv.y, w1.z, acc.z); acc.w = fmaf(hv.y, w1.w, acc.w);
        acc.x = fmaf(hv.z, w2.x, acc.x); acc.y = fmaf(hv.z, w2.y, acc.y);
        acc.z = fmaf(hv.z, w2.z, acc.z); acc.w = fmaf(hv.z, w2.w, acc.w);
        acc.x = fmaf(hv.w, w3.x, acc.x); acc.y = fmaf(hv.w, w3.y, acc.y);
        acc.z = fmaf(hv.w, w3.z, acc.z); acc.w = fmaf(hv.w, w3.w, acc.w);
    }
    float4 bv = *reinterpret_cast<const float4*>(bias + c4);
    acc.x += bv.x; acc.y += bv.y; acc.z += bv.z; acc.w += bv.w;
    if (RELU) {
        acc.x = fmaxf(acc.x, 0.f); acc.y = fmaxf(acc.y, 0.f);
        acc.z = fmaxf(acc.z, 0.f); acc.w = fmaxf(acc.w, 0.f);
    }
    *reinterpret_cast<float4*>(out + (size_t)row * NDIM + c4) = acc;
}

extern "C" void kernel_launch(void* const* d_in, const int* in_sizes, int n_in,
                              void* d_out, int out_size, void* d_ws, size_t ws_size,
                              hipStream_t stream) {
    const float* features = (const float*)d_in[0];
    const int*   src      = (const int*)d_in[1];
    const int*   dst      = (const int*)d_in[2];
    const float* W1       = (const float*)d_in[3];
    const float* b1       = (const float*)d_in[4];
    const float* W2       = (const float*)d_in[5];
    const float* b2       = (const float*)d_in[6];
    float* out = (float*)d_out;

    int n_nodes = in_sizes[0] / NDIM;   // 50000
    int n_edges = in_sizes[1];          // 800000
    int nbk = (n_nodes + BKT_NODES - 1) >> BKT_SHIFT;   // 196
    int ntiles = (n_edges + TILE - 1) / TILE;           // 196
    int rp_pad = ((n_nodes + 1 + 3) / 4) * 4;

    // ---- ws layout ----
    char* base = (char*)d_ws;
    unsigned short* hneigh_bf = (unsigned short*)base;                     // N*128 bf16
    unsigned short* w1_bf  = hneigh_bf + (size_t)n_nodes * NDIM;           // 16384
    unsigned short* w2_bf  = w1_bf + NDIM * NDIM;                          // 16384
    int*   row_ptr = (int*)(w2_bf + NDIM * NDIM);                          // rp_pad
    int*   col     = row_ptr + rp_pad;                                     // E
    unsigned short* feat_bf = (unsigned short*)(col + n_edges);            // N*128 bf16
    int*      hist_g = (int*)(feat_bf + (size_t)n_nodes * NDIM);           // nbk*ntiles
    int*      bbase  = hist_g + (size_t)nbk * ntiles;                      // nbk
    int*      tsums  = bbase + ((nbk + 3) / 4) * 4;                        // 128
    unsigned* bdata  = (unsigned*)(tsums + 128);                           // E
    // fallback-only
    float* WT1    = (float*)(bdata + n_edges);
    float* WT2    = WT1 + NDIM * NDIM;
    int*   counts = (int*)(WT2 + NDIM * NDIM);
    int*   cursor = counts + n_nodes;
    float* hneigh_f = (float*)(cursor + n_nodes);

    size_t needed_fast = (char*)(bdata + n_edges) - base;
    size_t needed_fb   = (char*)(hneigh_f + (size_t)n_nodes * NDIM) - base;

    unsigned short* h1_bf = (unsigned short*)d_out;

    int eb = (n_edges + 255) / 256;
    int nscan = nbk * ntiles;
    int nsb = (nscan + SCAN_BS - 1) / SCAN_BS;
    bool fast = (ws_size >= needed_fast) && (n_nodes <= 65536)
              && (nbk <= NBK_MAX) && (nsb <= 128);

    if (fast) {
        int n8 = n_nodes * (NDIM / 8);
        convert_all<<<(n8 + 4096 + 255) / 256, 256, 0, stream>>>(
            features, W1, W2, feat_bf, w1_bf, w2_bf, n8);

        // ---- CSR build (5 kernels) ----
        tile_hist<<<ntiles, 256, 0, stream>>>(dst, hist_g, n_edges, ntiles, nbk);
        scan_g_local<<<nsb, SCAN_BS, 0, stream>>>(hist_g, tsums, nscan);
        scan_g_apply2<<<nsb, SCAN_BS, 0, stream>>>(hist_g, tsums, bbase, nscan, ntiles, nbk);
        tile_scatter<<<ntiles, 256, 0, stream>>>(src, dst, hist_g, bdata,
                                                 n_edges, ntiles, nbk);
        bucket_sort_rp<<<nbk, 256, 0, stream>>>(bbase, bdata, row_ptr, col,
                                                n_nodes, n_edges, nbk);

        int ab = (int)(((long)n_nodes * 64 + 255) / 256);
        int lb = (n_nodes + 127) / 128;

        // ---- Layer 1 ----
        aggregate_bf<<<ab, 256, 0, stream>>>((const uint4*)feat_bf, row_ptr, col,
                                             (uint4*)hneigh_bf, n_nodes);
        linear_mfma<true, true><<<lb, 256, 0, stream>>>(hneigh_bf, w1_bf, b1,
                                                        nullptr, h1_bf, n_nodes);
        // ---- Layer 2 ----
        aggregate_bf<<<ab, 256, 0, stream>>>((const uint4*)h1_bf, row_ptr, col,
                                             (uint4*)hneigh_bf, n_nodes);
        linear_mfma<false, false><<<lb, 256, 0, stream>>>(hneigh_bf, w2_bf, b2,
                                                          out, nullptr, n_nodes);
    } else if (ws_size >= needed_fb) {
        // ---- f32 fallback ----
        transpose_w2<<<128, 256, 0, stream>>>(W1, W2, WT1, WT2);
        hipMemsetAsync(counts, 0, (size_t)n_nodes * sizeof(int), stream);
        hist_dst<<<eb, 256, 0, stream>>>(dst, counts, n_edges);
        int nb = (n_nodes + SCAN_BS - 1) / SCAN_BS;
        scan_g_local<<<nb, SCAN_BS, 0, stream>>>(counts, tsums, n_nodes);
        scan_blocksums<<<1, 128, 0, stream>>>(tsums, nb);
        scan_apply_fb<<<nb, SCAN_BS, 0, stream>>>(counts, cursor, tsums, n_nodes, nb);
        hipMemcpyAsync(row_ptr, counts, (size_t)(n_nodes + 1) * sizeof(int),
                       hipMemcpyDeviceToDevice, stream);
        fill_csr<<<eb, 256, 0, stream>>>(src, dst, cursor, col, n_edges);

        int ab = (int)(((long)n_nodes * 64 + 255) / 256);
        int lk = (n_nodes * 32 + 255) / 256;
        aggregate<<<ab, 256, 0, stream>>>(features, row_ptr, col, hneigh_f, n_nodes);
        linear_k<true><<<lk, 256, 0, stream>>>(hneigh_f, WT1, b1, out, n_nodes);
        aggregate<<<ab, 256, 0, stream>>>(out, row_ptr, col, hneigh_f, n_nodes);
        linear_k<false><<<lk, 256, 0, stream>>>(hneigh_f, WT2, b2, out, n_nodes);
    }
}

// Round 14
// 145.224 us; speedup vs baseline: 1.5788x; 1.0237x over previous
//
#include <hip/hip_runtime.h>

// MPNN: h1 = relu(segsum(feat[src] -> dst) @ W1^T + b1)
//       out = segsum(h1[src] -> dst) @ W2^T + b2
// N=50000, E=800000, d=128.
//
// Round 13->14: (a) aggregate gather pipelined 4-deep (preload 4 col indices,
// 4 independent 64B row loads in flight per lane; mean degree 16 = 4/slot so
// one batch covers a typical node); (b) convert_all fused into tile_hist via
// block-role split (one fewer dispatch; BW-bound convert overlaps atomic-bound
// histogram). Everything else = round-13 (148.7us).

#define NDIM 128
#define SCAN_BS 512
#define BKT_SHIFT 8                 // 256 nodes per bucket
#define BKT_NODES 256
#define TILE 4096
#define NBK_MAX 256

typedef __attribute__((ext_vector_type(8))) short bf16x8;
typedef __attribute__((ext_vector_type(4))) float f32x4;

__device__ inline unsigned short f2bf_rne(float x) {
    unsigned u = __float_as_uint(x);
    unsigned lsb = (u >> 16) & 1u;
    u += 0x7fffu + lsb;
    return (unsigned short)(u >> 16);
}

__device__ inline unsigned pack_bf2(float lo, float hi) {
    return (unsigned)f2bf_rne(lo) | ((unsigned)f2bf_rne(hi) << 16);
}

// ====== fused: tile histogram (blocks [0,ntiles)) + f32->bf16 convert ======
__global__ __launch_bounds__(256) void hist_convert(
        const int* __restrict__ dst, int* __restrict__ hist_g,
        int n_edges, int ntiles, int nbk,
        const float* __restrict__ feat, const float* __restrict__ W1,
        const float* __restrict__ W2,
        unsigned short* __restrict__ feat_bf,
        unsigned short* __restrict__ w1_bf,
        unsigned short* __restrict__ w2_bf, int n8) {
    __shared__ int lh[NBK_MAX];
    int t = threadIdx.x;
    if (blockIdx.x < (unsigned)ntiles) {
        // ---- histogram role ----
        int tblk = blockIdx.x;
        for (int i = t; i < nbk; i += 256) lh[i] = 0;
        __syncthreads();
        int e0 = tblk * TILE;
        int e1 = min(e0 + TILE, n_edges);
        for (int e = e0 + t; e < e1; e += 256)
            atomicAdd(&lh[dst[e] >> BKT_SHIFT], 1);
        __syncthreads();
        for (int i = t; i < nbk; i += 256)
            hist_g[i * ntiles + tblk] = lh[i];
    } else {
        // ---- convert role ----
        int i = (blockIdx.x - ntiles) * 256 + t;
        const float* srcp;
        unsigned short* dstp;
        int j;
        if (i < n8)             { srcp = feat; dstp = feat_bf; j = i; }
        else if (i < n8 + 2048) { srcp = W1;   dstp = w1_bf;   j = i - n8; }
        else if (i < n8 + 4096) { srcp = W2;   dstp = w2_bf;   j = i - n8 - 2048; }
        else return;
        const float4* p = reinterpret_cast<const float4*>(srcp + (size_t)j * 8);
        float4 a = p[0], b = p[1];
        uint4 pk;
        pk.x = pack_bf2(a.x, a.y);
        pk.y = pack_bf2(a.z, a.w);
        pk.z = pack_bf2(b.x, b.y);
        pk.w = pack_bf2(b.z, b.w);
        *reinterpret_cast<uint4*>(dstp + (size_t)j * 8) = pk;
    }
}

__global__ __launch_bounds__(SCAN_BS) void scan_g_local(int* g, int* tsums, int n) {
    __shared__ int sh[SCAN_BS];
    int t = threadIdx.x;
    int i = blockIdx.x * SCAN_BS + t;
    int v = (i < n) ? g[i] : 0;
    sh[t] = v;
    __syncthreads();
    for (int off = 1; off < SCAN_BS; off <<= 1) {
        int u = (t >= off) ? sh[t - off] : 0;
        __syncthreads();
        sh[t] += u;
        __syncthreads();
    }
    if (i < n) g[i] = sh[t] - v;
    if (t == SCAN_BS - 1) tsums[blockIdx.x] = sh[t];
}

// apply with inline offset: block b tree-reduces tsums[0..b) in LDS. grid <=128.
__global__ __launch_bounds__(SCAN_BS) void scan_g_apply2(int* g, const int* tsums,
                                                         int* bbase, int n,
                                                         int ntiles, int nbk) {
    __shared__ int part[128];
    int t = threadIdx.x;
    int b = blockIdx.x;
    if (t < 128) part[t] = (t < b) ? tsums[t] : 0;
    __syncthreads();
    for (int off = 64; off > 0; off >>= 1) {
        if (t < off) part[t] += part[t + off];
        __syncthreads();
    }
    int add = part[0];
    int i = b * SCAN_BS + t;
    if (i >= n) return;
    int r = g[i] + add;
    g[i] = r;
    if (i % ntiles == 0) {
        int bk = i / ntiles;
        if (bk < nbk) bbase[bk] = r;
    }
}

__global__ __launch_bounds__(128) void scan_blocksums(int* __restrict__ block_sums, int nb) {
    __shared__ int sh[128];
    int t = threadIdx.x;
    sh[t] = (t < nb) ? block_sums[t] : 0;
    __syncthreads();
    for (int off = 1; off < 128; off <<= 1) {
        int u = (t >= off) ? sh[t - off] : 0;
        __syncthreads();
        sh[t] += u;
        __syncthreads();
    }
    if (t < nb) block_sums[t] = sh[t];
}

__global__ __launch_bounds__(256) void tile_scatter(const int* __restrict__ src,
                                                    const int* __restrict__ dst,
                                                    const int* __restrict__ hist_g,
                                                    unsigned* __restrict__ bdata,
                                                    int n_edges, int ntiles, int nbk) {
    __shared__ int lcur[NBK_MAX];
    __shared__ int lbase[NBK_MAX];
    __shared__ int gbase[NBK_MAX];
    __shared__ unsigned sorted[TILE];
    int tblk = blockIdx.x;
    int t = threadIdx.x;
    for (int i = t; i < nbk; i += 256) lcur[i] = 0;
    __syncthreads();
    int e0 = tblk * TILE;
    int e1 = min(e0 + TILE, n_edges);
    for (int e = e0 + t; e < e1; e += 256)
        atomicAdd(&lcur[dst[e] >> BKT_SHIFT], 1);
    __syncthreads();
    if (t == 0) {
        int run = 0;
        for (int b = 0; b < nbk; ++b) { lbase[b] = run; run += lcur[b]; }
    }
    __syncthreads();
    for (int i = t; i < nbk; i += 256) {
        gbase[i] = hist_g[i * ntiles + tblk];
        lcur[i]  = lbase[i];
    }
    __syncthreads();
    for (int e = e0 + t; e < e1; e += 256) {
        int d = dst[e];
        int s = src[e];
        int b = d >> BKT_SHIFT;
        int p = atomicAdd(&lcur[b], 1);
        sorted[p] = (unsigned)(s & 0xFFFF) | ((unsigned)(d & (BKT_NODES - 1)) << 16)
                  | ((unsigned)b << 24);
    }
    __syncthreads();
    int cnt = e1 - e0;
    for (int j = t; j < cnt; j += 256) {
        unsigned pk = sorted[j];
        int b = pk >> 24;
        bdata[gbase[b] + (j - lbase[b])] = pk;
    }
}

__global__ __launch_bounds__(256) void bucket_sort_rp(const int* __restrict__ bbase,
                                                      const unsigned* __restrict__ bdata,
                                                      int* __restrict__ row_ptr,
                                                      int* __restrict__ col,
                                                      int n_nodes, int n_edges, int nbk) {
    __shared__ int lcnt[BKT_NODES];
    __shared__ int lcur[BKT_NODES];
    int b = blockIdx.x;
    int t = threadIdx.x;
    int node0 = b << BKT_SHIFT;
    int nloc = min(BKT_NODES, n_nodes - node0);
    int base = bbase[b];
    int next = (b + 1 < nbk) ? bbase[b + 1] : n_edges;
    int cnt = next - base;
    lcnt[t] = 0;
    __syncthreads();
    for (int i = t; i < cnt; i += 256)
        atomicAdd(&lcnt[(bdata[base + i] >> 16) & 255], 1);
    __syncthreads();
    int v = lcnt[t];
    lcur[t] = v;
    __syncthreads();
    for (int off = 1; off < 256; off <<= 1) {
        int u = (t >= off) ? lcur[t - off] : 0;
        __syncthreads();
        lcur[t] += u;
        __syncthreads();
    }
    int excl = lcur[t] - v;
    __syncthreads();
    lcur[t] = excl;
    if (t < nloc) row_ptr[node0 + t] = base + excl;
    if (b == nbk - 1 && t == 0) row_ptr[n_nodes] = n_edges;
    __syncthreads();
    for (int i = t; i < cnt; i += 256) {
        unsigned pk = bdata[base + i];
        int pos = atomicAdd(&lcur[(pk >> 16) & 255], 1);
        col[base + pos] = pk & 0xFFFF;
    }
}

// ---------------- bf16 gather segment sum, 4-deep pipelined ----------------
// One wave per dst node; 16 lanes/edge (4 edge slots), 16B/lane.
__global__ void aggregate_bf(const uint4* __restrict__ feat_bf,   // [N][16] uint4
                             const int* __restrict__ row_ptr,
                             const int* __restrict__ col,
                             uint4* __restrict__ out_bf,          // [N][16] uint4 (bf16)
                             int n_nodes) {
    int wid  = (blockIdx.x * blockDim.x + threadIdx.x) >> 6;
    int lane = threadIdx.x & 63;
    if (wid >= n_nodes) return;
    int sub = lane >> 4;            // edge slot 0..3
    int d   = lane & 15;            // 16B chunk within row
    int beg = row_ptr[wid];
    int end = row_ptr[wid + 1];
    float acc[8] = {0.f,0.f,0.f,0.f,0.f,0.f,0.f,0.f};

    int e = beg + sub;
    // 4 loads in flight per lane (16 edges per batch across slots)
    for (; e + 12 < end; e += 16) {
        int s0 = col[e];
        int s1 = col[e + 4];
        int s2 = col[e + 8];
        int s3 = col[e + 12];
        uint4 a0 = feat_bf[(size_t)s0 * 16 + d];
        uint4 a1 = feat_bf[(size_t)s1 * 16 + d];
        uint4 a2 = feat_bf[(size_t)s2 * 16 + d];
        uint4 a3 = feat_bf[(size_t)s3 * 16 + d];
        unsigned w0[4] = {a0.x, a0.y, a0.z, a0.w};
        unsigned w1[4] = {a1.x, a1.y, a1.z, a1.w};
        unsigned w2[4] = {a2.x, a2.y, a2.z, a2.w};
        unsigned w3[4] = {a3.x, a3.y, a3.z, a3.w};
#pragma unroll
        for (int j = 0; j < 4; ++j) {
            acc[2*j]   += __uint_as_float(w0[j] << 16);
            acc[2*j+1] += __uint_as_float(w0[j] & 0xFFFF0000u);
            acc[2*j]   += __uint_as_float(w1[j] << 16);
            acc[2*j+1] += __uint_as_float(w1[j] & 0xFFFF0000u);
            acc[2*j]   += __uint_as_float(w2[j] << 16);
            acc[2*j+1] += __uint_as_float(w2[j] & 0xFFFF0000u);
            acc[2*j]   += __uint_as_float(w3[j] << 16);
            acc[2*j+1] += __uint_as_float(w3[j] & 0xFFFF0000u);
        }
    }
    // 2-deep tail
    for (; e + 4 < end; e += 8) {
        int s0 = col[e];
        int s1 = col[e + 4];
        uint4 a0 = feat_bf[(size_t)s0 * 16 + d];
        uint4 a1 = feat_bf[(size_t)s1 * 16 + d];
        unsigned w0[4] = {a0.x, a0.y, a0.z, a0.w};
        unsigned w1[4] = {a1.x, a1.y, a1.z, a1.w};
#pragma unroll
        for (int j = 0; j < 4; ++j) {
            acc[2*j]   += __uint_as_float(w0[j] << 16);
            acc[2*j+1] += __uint_as_float(w0[j] & 0xFFFF0000u);
            acc[2*j]   += __uint_as_float(w1[j] << 16);
            acc[2*j+1] += __uint_as_float(w1[j] & 0xFFFF0000u);
        }
    }
    if (e < end) {
        int s0 = col[e];
        uint4 a0 = feat_bf[(size_t)s0 * 16 + d];
        unsigned w0[4] = {a0.x, a0.y, a0.z, a0.w};
#pragma unroll
        for (int j = 0; j < 4; ++j) {
            acc[2*j]   += __uint_as_float(w0[j] << 16);
            acc[2*j+1] += __uint_as_float(w0[j] & 0xFFFF0000u);
        }
    }
#pragma unroll
    for (int j = 0; j < 8; ++j) {
        acc[j] += __shfl_xor(acc[j], 16, 64);
        acc[j] += __shfl_xor(acc[j], 32, 64);
    }
    if (sub == 0) {
        uint4 pk;
        pk.x = pack_bf2(acc[0], acc[1]);
        pk.y = pack_bf2(acc[2], acc[3]);
        pk.z = pack_bf2(acc[4], acc[5]);
        pk.w = pack_bf2(acc[6], acc[7]);
        out_bf[(size_t)wid * 16 + d] = pk;
    }
}

// ---------------- bf16 MFMA linear: out = h @ W^T + b ----------------
template <bool RELU, bool OUTBF>
__global__ __launch_bounds__(256) void linear_mfma(const unsigned short* __restrict__ h_bf,
                                                   const unsigned short* __restrict__ w_bf,
                                                   const float* __restrict__ bias,
                                                   float* __restrict__ out_f,
                                                   unsigned short* __restrict__ out_bf,
                                                   int n_nodes) {
    int t = threadIdx.x;
    int lane = t & 63;
    int wv = t >> 6;                       // 0..3
    int r0 = blockIdx.x * 128 + wv * 32;
    int n1 = n_nodes - 1;
    int ra0 = min(r0 + (lane & 15), n1);
    int ra1 = min(r0 + 16 + (lane & 15), n1);
    int kb = (lane >> 4) * 8;
    int colb = lane & 15;

    f32x4 acc[2][8];
#pragma unroll
    for (int fr = 0; fr < 2; ++fr)
#pragma unroll
        for (int c = 0; c < 8; ++c)
            acc[fr][c] = (f32x4){0.f, 0.f, 0.f, 0.f};

#pragma unroll
    for (int kc = 0; kc < NDIM; kc += 32) {
        bf16x8 a0 = *reinterpret_cast<const bf16x8*>(h_bf + (size_t)ra0 * NDIM + kc + kb);
        bf16x8 a1 = *reinterpret_cast<const bf16x8*>(h_bf + (size_t)ra1 * NDIM + kc + kb);
#pragma unroll
        for (int c = 0; c < 8; ++c) {
            bf16x8 b = *reinterpret_cast<const bf16x8*>(
                w_bf + (size_t)(c * 16 + colb) * NDIM + kc + kb);
            acc[0][c] = __builtin_amdgcn_mfma_f32_16x16x32_bf16(a0, b, acc[0][c], 0, 0, 0);
            acc[1][c] = __builtin_amdgcn_mfma_f32_16x16x32_bf16(a1, b, acc[1][c], 0, 0, 0);
        }
    }

    int orow = (lane >> 4) * 4;
#pragma unroll
    for (int fr = 0; fr < 2; ++fr) {
#pragma unroll
        for (int c = 0; c < 8; ++c) {
            int colg = c * 16 + colb;
            float bv = bias[colg];
#pragma unroll
            for (int reg = 0; reg < 4; ++reg) {
                int row = r0 + fr * 16 + orow + reg;
                if (row >= n_nodes) continue;
                float v = acc[fr][c][reg] + bv;
                if (RELU) v = fmaxf(v, 0.f);
                if (OUTBF) out_bf[(size_t)row * NDIM + colg] = f2bf_rne(v);
                else       out_f[(size_t)row * NDIM + colg] = v;
            }
        }
    }
}

// ================= fallback CSR build + f32 path (safety only) =================
__global__ void hist_dst(const int* __restrict__ dst, int* __restrict__ counts, int n_edges) {
    int i = blockIdx.x * blockDim.x + threadIdx.x;
    if (i < n_edges) atomicAdd(&counts[dst[i]], 1);
}

__global__ __launch_bounds__(SCAN_BS) void scan_apply_fb(int* __restrict__ row_ptr,
                                                         int* __restrict__ cursor,
                                                         const int* __restrict__ block_sums,
                                                         int n, int nb) {
    int b = blockIdx.x;
    int i = b * SCAN_BS + threadIdx.x;
    int add = (b == 0) ? 0 : block_sums[b - 1];
    if (i < n) {
        int r = row_ptr[i] + add;
        row_ptr[i] = r;
        cursor[i]  = r;
    }
    if (i == 0) row_ptr[n] = block_sums[nb - 1];
}

__global__ void fill_csr(const int* __restrict__ src, const int* __restrict__ dst,
                         int* __restrict__ cursor, int* __restrict__ col, int n_edges) {
    int i = blockIdx.x * blockDim.x + threadIdx.x;
    if (i < n_edges) {
        int pos = atomicAdd(&cursor[dst[i]], 1);
        col[pos] = src[i];
    }
}

__global__ void transpose_w2(const float* __restrict__ W1, const float* __restrict__ W2,
                             float* __restrict__ WT1, float* __restrict__ WT2) {
    int tid = blockIdx.x * 256 + threadIdx.x;
    int which = tid >> 14;
    int t = tid & 16383;
    int o = t >> 7;
    int i = t & 127;
    if (which == 0) WT1[i * NDIM + o] = W1[o * NDIM + i];
    else            WT2[i * NDIM + o] = W2[o * NDIM + i];
}

__global__ void aggregate(const float* __restrict__ feat,
                          const int* __restrict__ row_ptr,
                          const int* __restrict__ col,
                          float* __restrict__ out, int n_nodes) {
    int wid  = (blockIdx.x * blockDim.x + threadIdx.x) >> 6;
    int lane = threadIdx.x & 63;
    if (wid >= n_nodes) return;
    int half = lane >> 5;
    int d4   = (lane & 31) << 2;
    int beg = row_ptr[wid];
    int end = row_ptr[wid + 1];
    float ax = 0.f, ay = 0.f, az = 0.f, aw = 0.f;
    int k = beg + half;
    for (; k < end; k += 2) {
        int s0 = col[k];
        float4 v0 = *reinterpret_cast<const float4*>(feat + (size_t)s0 * NDIM + d4);
        ax += v0.x; ay += v0.y; az += v0.z; aw += v0.w;
    }
    ax += __shfl(ax, lane ^ 32, 64);
    ay += __shfl(ay, lane ^ 32, 64);
    az += __shfl(az, lane ^ 32, 64);
    aw += __shfl(aw, lane ^ 32, 64);
    if (half == 0) {
        float4 r; r.x = ax; r.y = ay; r.z = az; r.w = aw;
        *reinterpret_cast<float4*>(out + (size_t)wid * NDIM + d4) = r;
    }
}

template <bool RELU>
__global__ void linear_k(const float* __restrict__ h, const float* __restrict__ WT,
                         const float* __restrict__ bias, float* __restrict__ out,
                         int n_nodes) {
    int tid = blockIdx.x * blockDim.x + threadIdx.x;
    int row = tid >> 5;
    if (row >= n_nodes) return;
    int c4 = (tid & 31) << 2;
    const float4* h4 = reinterpret_cast<const float4*>(h + (size_t)row * NDIM);
    float4 acc = make_float4(0.f, 0.f, 0.f, 0.f);
#pragma unroll 8
    for (int k4 = 0; k4 < 32; ++k4) {
        float4 hv = h4[k4];
        const float* wt = WT + (k4 * 4) * NDIM + c4;
        float4 w0 = *reinterpret_cast<const float4*>(wt);
        float4 w1 = *reinterpret_cast<const float4*>(wt + NDIM);
        float4 w2 = *reinterpret_cast<const float4*>(wt + 2 * NDIM);
        float4 w3 = *reinterpret_cast<const float4*>(wt + 3 * NDIM);
        acc.x = fmaf(hv.x, w0.x, acc.x); acc.y = fmaf(hv.x, w0.y, acc.y);
        acc.z = fmaf(hv.x, w0.z, acc.z); acc.w = fmaf(hv.x, w0.w, acc.w);
        acc.x = fmaf(hv.y, w1.x, acc.x); acc.y = fmaf(hv.y, w1.y, acc.y);
        acc.z = fmaf(hv.y, w1.z, acc.z); acc.w = fmaf(hv.y, w1.w, acc.w);
        acc.x = fmaf(hv.z, w2.x, acc.x); acc.y = fmaf(hv.z, w2.y, acc.y);
        acc.z = fmaf(hv.z, w2.z, acc.z); acc.w = fmaf(hv.z, w2.w, acc.w);
        acc.x = fmaf(hv.w, w3.x, acc.x); acc.y = fmaf(hv.w, w3.y, acc.y);
        acc.z = fmaf(hv.w, w3.z, acc.z); acc.w = fmaf(hv.w, w3.w, acc.w);
    }
    float4 bv = *reinterpret_cast<const float4*>(bias + c4);
    acc.x += bv.x; acc.y += bv.y; acc.z += bv.z; acc.w += bv.w;
    if (RELU) {
        acc.x = fmaxf(acc.x, 0.f); acc.y = fmaxf(acc.y, 0.f);
        acc.z = fmaxf(acc.z, 0.f); acc.w = fmaxf(acc.w, 0.f);
    }
    *reinterpret_cast<float4*>(out + (size_t)row * NDIM + c4) = acc;
}

extern "C" void kernel_launch(void* const* d_in, const int* in_sizes, int n_in,
                              void* d_out, int out_size, void* d_ws, size_t ws_size,
                              hipStream_t stream) {
    const float* features = (const float*)d_in[0];
    const int*   src      = (const int*)d_in[1];
    const int*   dst      = (const int*)d_in[2];
    const float* W1       = (const float*)d_in[3];
    const float* b1       = (const float*)d_in[4];
    const float* W2       = (const float*)d_in[5];
    const float* b2       = (const float*)d_in[6];
    float* out = (float*)d_out;

    int n_nodes = in_sizes[0] / NDIM;   // 50000
    int n_edges = in_sizes[1];          // 800000
    int nbk = (n_nodes + BKT_NODES - 1) >> BKT_SHIFT;   // 196
    int ntiles = (n_edges + TILE - 1) / TILE;           // 196
    int rp_pad = ((n_nodes + 1 + 3) / 4) * 4;

    // ---- ws layout ----
    char* base = (char*)d_ws;
    unsigned short* hneigh_bf = (unsigned short*)base;                     // N*128 bf16
    unsigned short* w1_bf  = hneigh_bf + (size_t)n_nodes * NDIM;           // 16384
    unsigned short* w2_bf  = w1_bf + NDIM * NDIM;                          // 16384
    int*   row_ptr = (int*)(w2_bf + NDIM * NDIM);                          // rp_pad
    int*   col     = row_ptr + rp_pad;                                     // E
    unsigned short* feat_bf = (unsigned short*)(col + n_edges);            // N*128 bf16
    int*      hist_g = (int*)(feat_bf + (size_t)n_nodes * NDIM);           // nbk*ntiles
    int*      bbase  = hist_g + (size_t)nbk * ntiles;                      // nbk
    int*      tsums  = bbase + ((nbk + 3) / 4) * 4;                        // 128
    unsigned* bdata  = (unsigned*)(tsums + 128);                           // E
    // fallback-only
    float* WT1    = (float*)(bdata + n_edges);
    float* WT2    = WT1 + NDIM * NDIM;
    int*   counts = (int*)(WT2 + NDIM * NDIM);
    int*   cursor = counts + n_nodes;
    float* hneigh_f = (float*)(cursor + n_nodes);

    size_t needed_fast = (char*)(bdata + n_edges) - base;
    size_t needed_fb   = (char*)(hneigh_f + (size_t)n_nodes * NDIM) - base;

    unsigned short* h1_bf = (unsigned short*)d_out;

    int eb = (n_edges + 255) / 256;
    int nscan = nbk * ntiles;
    int nsb = (nscan + SCAN_BS - 1) / SCAN_BS;
    bool fast = (ws_size >= needed_fast) && (n_nodes <= 65536)
              && (nbk <= NBK_MAX) && (nsb <= 128);

    if (fast) {
        int n8 = n_nodes * (NDIM / 8);
        int cvt_blocks = (n8 + 4096 + 255) / 256;

        // ---- fused hist + convert, then scan/scatter/sort ----
        hist_convert<<<ntiles + cvt_blocks, 256, 0, stream>>>(
            dst, hist_g, n_edges, ntiles, nbk,
            features, W1, W2, feat_bf, w1_bf, w2_bf, n8);
        scan_g_local<<<nsb, SCAN_BS, 0, stream>>>(hist_g, tsums, nscan);
        scan_g_apply2<<<nsb, SCAN_BS, 0, stream>>>(hist_g, tsums, bbase, nscan, ntiles, nbk);
        tile_scatter<<<ntiles, 256, 0, stream>>>(src, dst, hist_g, bdata,
                                                 n_edges, ntiles, nbk);
        bucket_sort_rp<<<nbk, 256, 0, stream>>>(bbase, bdata, row_ptr, col,
                                                n_nodes, n_edges, nbk);

        int ab = (int)(((long)n_nodes * 64 + 255) / 256);
        int lb = (n_nodes + 127) / 128;

        // ---- Layer 1 ----
        aggregate_bf<<<ab, 256, 0, stream>>>((const uint4*)feat_bf, row_ptr, col,
                                             (uint4*)hneigh_bf, n_nodes);
        linear_mfma<true, true><<<lb, 256, 0, stream>>>(hneigh_bf, w1_bf, b1,
                                                        nullptr, h1_bf, n_nodes);
        // ---- Layer 2 ----
        aggregate_bf<<<ab, 256, 0, stream>>>((const uint4*)h1_bf, row_ptr, col,
                                             (uint4*)hneigh_bf, n_nodes);
        linear_mfma<false, false><<<lb, 256, 0, stream>>>(hneigh_bf, w2_bf, b2,
                                                          out, nullptr, n_nodes);
    } else if (ws_size >= needed_fb) {
        // ---- f32 fallback ----
        transpose_w2<<<128, 256, 0, stream>>>(W1, W2, WT1, WT2);
        hipMemsetAsync(counts, 0, (size_t)n_nodes * sizeof(int), stream);
        hist_dst<<<eb, 256, 0, stream>>>(dst, counts, n_edges);
        int nb = (n_nodes + SCAN_BS - 1) / SCAN_BS;
        scan_g_local<<<nb, SCAN_BS, 0, stream>>>(counts, tsums, n_nodes);
        scan_blocksums<<<1, 128, 0, stream>>>(tsums, nb);
        scan_apply_fb<<<nb, SCAN_BS, 0, stream>>>(counts, cursor, tsums, n_nodes, nb);
        hipMemcpyAsync(row_ptr, counts, (size_t)(n_nodes + 1) * sizeof(int),
                       hipMemcpyDeviceToDevice, stream);
        fill_csr<<<eb, 256, 0, stream>>>(src, dst, cursor, col, n_edges);

        int ab = (int)(((long)n_nodes * 64 + 255) / 256);
        int lk = (n_nodes * 32 + 255) / 256;
        aggregate<<<ab, 256, 0, stream>>>(features, row_ptr, col, hneigh_f, n_nodes);
        linear_k<true><<<lk, 256, 0, stream>>>(hneigh_f, WT1, b1, out, n_nodes);
        aggregate<<<ab, 256, 0, stream>>>(out, row_ptr, col, hneigh_f, n_nodes);
        linear_k<false><<<lk, 256, 0, stream>>>(hneigh_f, WT2, b2, out, n_nodes);
    }
}